// Round 1
// baseline (167.179 us; speedup 1.0000x reference)
//
#include <hip/hip_runtime.h>
#include <cmath>

#define NB    32
#define CH    384
#define IH    64
#define IW    64
#define OH    32
#define OW    32
#define PH    70   // padded LDS plane: rows/cols -3..66

// ---------------------------------------------------------------------------
// Pass 1: depthwise conv (both branches), accumulate per-channel sum & sumsq.
// One block per (n,c) input plane. 256 threads, 4 output pixels each.
// ---------------------------------------------------------------------------
__global__ __launch_bounds__(256) void conv_stats_kernel(
    const float* __restrict__ x,
    const float* __restrict__ w_lk,
    const float* __restrict__ w_sk,
    float* __restrict__ stats)   // [CH][4] = {sum_lk, sumsq_lk, sum_sk, sumsq_sk}
{
    __shared__ float sx[PH * PH];
    __shared__ float swl[49];
    __shared__ float sws[9];
    __shared__ float sred[4 * 4];

    const int nc = blockIdx.x;
    const int c  = nc % CH;
    const float* xp = x + (size_t)nc * (IH * IW);
    const int tid = threadIdx.x;

    // zero halo, then fill interior (coalesced global reads)
    for (int i = tid; i < PH * PH; i += 256) sx[i] = 0.0f;
    __syncthreads();
    for (int i = tid; i < IH * IW; i += 256) {
        int r = i >> 6, cl = i & 63;
        sx[(r + 3) * PH + (cl + 3)] = xp[i];
    }
    if (tid < 49) swl[tid] = w_lk[c * 49 + tid];
    if (tid < 9)  sws[tid] = w_sk[c * 9 + tid];
    __syncthreads();

    float s0 = 0.f, s1 = 0.f, s2 = 0.f, s3 = 0.f;
    for (int p = tid; p < OH * OW; p += 256) {
        const int oy = p >> 5, ox = p & 31;
        const int iy = oy * 2, ix = ox * 2;   // padded coords for 7x7 (pad 3)
        float acc_l = 0.f;
#pragma unroll
        for (int ky = 0; ky < 7; ++ky)
#pragma unroll
            for (int kx = 0; kx < 7; ++kx)
                acc_l = fmaf(sx[(iy + ky) * PH + ix + kx], swl[ky * 7 + kx], acc_l);
        float acc_s = 0.f;
#pragma unroll
        for (int ky = 0; ky < 3; ++ky)        // 3x3 (pad 1): +2 offset in padded coords
#pragma unroll
            for (int kx = 0; kx < 3; ++kx)
                acc_s = fmaf(sx[(iy + 2 + ky) * PH + ix + 2 + kx], sws[ky * 3 + kx], acc_s);
        s0 += acc_l; s1 += acc_l * acc_l;
        s2 += acc_s; s3 += acc_s * acc_s;
    }

    // wave64 reduce
#pragma unroll
    for (int off = 32; off >= 1; off >>= 1) {
        s0 += __shfl_down(s0, off);
        s1 += __shfl_down(s1, off);
        s2 += __shfl_down(s2, off);
        s3 += __shfl_down(s3, off);
    }
    const int wave = tid >> 6;
    if ((tid & 63) == 0) {
        sred[wave * 4 + 0] = s0; sred[wave * 4 + 1] = s1;
        sred[wave * 4 + 2] = s2; sred[wave * 4 + 3] = s3;
    }
    __syncthreads();
    if (tid == 0) {
        float t0 = 0.f, t1 = 0.f, t2 = 0.f, t3 = 0.f;
#pragma unroll
        for (int wv = 0; wv < 4; ++wv) {
            t0 += sred[wv * 4 + 0]; t1 += sred[wv * 4 + 1];
            t2 += sred[wv * 4 + 2]; t3 += sred[wv * 4 + 3];
        }
        atomicAdd(&stats[c * 4 + 0], t0);
        atomicAdd(&stats[c * 4 + 1], t1);
        atomicAdd(&stats[c * 4 + 2], t2);
        atomicAdd(&stats[c * 4 + 3], t3);
    }
}

// ---------------------------------------------------------------------------
// Pass 2: fold BN into per-channel scale/shift.
// ---------------------------------------------------------------------------
__global__ void finalize_kernel(
    const float* __restrict__ stats,
    const float* __restrict__ gamma_lk, const float* __restrict__ beta_lk,
    const float* __restrict__ gamma_sk, const float* __restrict__ beta_sk,
    float* __restrict__ params)  // [CH][4] = {sc_l, sh_l, sc_s, sh_s}
{
    const int c = blockIdx.x * blockDim.x + threadIdx.x;
    if (c >= CH) return;
    const float inv_cnt = 1.0f / (float)(NB * OH * OW);

    float mean_l = stats[c * 4 + 0] * inv_cnt;
    float var_l  = stats[c * 4 + 1] * inv_cnt - mean_l * mean_l;
    float sc_l   = gamma_lk[c] * rsqrtf(var_l + 1e-5f);
    float sh_l   = beta_lk[c] - mean_l * sc_l;

    float mean_s = stats[c * 4 + 2] * inv_cnt;
    float var_s  = stats[c * 4 + 3] * inv_cnt - mean_s * mean_s;
    float sc_s   = gamma_sk[c] * rsqrtf(var_s + 1e-5f);
    float sh_s   = beta_sk[c] - mean_s * sc_s;

    params[c * 4 + 0] = sc_l; params[c * 4 + 1] = sh_l;
    params[c * 4 + 2] = sc_s; params[c * 4 + 3] = sh_s;
}

// ---------------------------------------------------------------------------
// Pass 3: recompute convs (x now L3-resident), apply BN affine, add, GELU.
// ---------------------------------------------------------------------------
__global__ __launch_bounds__(256) void apply_kernel(
    const float* __restrict__ x,
    const float* __restrict__ w_lk,
    const float* __restrict__ w_sk,
    const float* __restrict__ params,
    float* __restrict__ out)
{
    __shared__ float sx[PH * PH];
    __shared__ float swl[49];
    __shared__ float sws[9];

    const int nc = blockIdx.x;
    const int c  = nc % CH;
    const float* xp = x + (size_t)nc * (IH * IW);
    float* op = out + (size_t)nc * (OH * OW);
    const int tid = threadIdx.x;

    for (int i = tid; i < PH * PH; i += 256) sx[i] = 0.0f;
    __syncthreads();
    for (int i = tid; i < IH * IW; i += 256) {
        int r = i >> 6, cl = i & 63;
        sx[(r + 3) * PH + (cl + 3)] = xp[i];
    }
    if (tid < 49) swl[tid] = w_lk[c * 49 + tid];
    if (tid < 9)  sws[tid] = w_sk[c * 9 + tid];
    __syncthreads();

    const float sc_l = params[c * 4 + 0];
    const float sh_l = params[c * 4 + 1];
    const float sc_s = params[c * 4 + 2];
    const float sh_s = params[c * 4 + 3];

    for (int p = tid; p < OH * OW; p += 256) {
        const int oy = p >> 5, ox = p & 31;
        const int iy = oy * 2, ix = ox * 2;
        float acc_l = 0.f;
#pragma unroll
        for (int ky = 0; ky < 7; ++ky)
#pragma unroll
            for (int kx = 0; kx < 7; ++kx)
                acc_l = fmaf(sx[(iy + ky) * PH + ix + kx], swl[ky * 7 + kx], acc_l);
        float acc_s = 0.f;
#pragma unroll
        for (int ky = 0; ky < 3; ++ky)
#pragma unroll
            for (int kx = 0; kx < 3; ++kx)
                acc_s = fmaf(sx[(iy + 2 + ky) * PH + ix + 2 + kx], sws[ky * 3 + kx], acc_s);

        float y = fmaf(acc_l, sc_l, sh_l) + fmaf(acc_s, sc_s, sh_s);
        // exact GELU: 0.5*y*(1+erf(y/sqrt(2)))
        float g = 0.5f * y * (1.0f + erff(y * 0.70710678118654752f));
        op[p] = g;
    }
}

extern "C" void kernel_launch(void* const* d_in, const int* in_sizes, int n_in,
                              void* d_out, int out_size, void* d_ws, size_t ws_size,
                              hipStream_t stream) {
    const float* x        = (const float*)d_in[0];
    const float* w_lk     = (const float*)d_in[1];
    const float* gamma_lk = (const float*)d_in[2];
    const float* beta_lk  = (const float*)d_in[3];
    const float* w_sk     = (const float*)d_in[4];
    const float* gamma_sk = (const float*)d_in[5];
    const float* beta_sk  = (const float*)d_in[6];
    float* out = (float*)d_out;

    float* stats  = (float*)d_ws;        // CH*4 floats
    float* params = stats + CH * 4;      // CH*4 floats

    hipMemsetAsync(stats, 0, CH * 4 * sizeof(float), stream);

    conv_stats_kernel<<<NB * CH, 256, 0, stream>>>(x, w_lk, w_sk, stats);
    finalize_kernel<<<(CH + 255) / 256, 256, 0, stream>>>(
        stats, gamma_lk, beta_lk, gamma_sk, beta_sk, params);
    apply_kernel<<<NB * CH, 256, 0, stream>>>(x, w_lk, w_sk, params, out);
}

// Round 2
// 121.376 us; speedup vs baseline: 1.3774x; 1.3774x over previous
//
#include <hip/hip_runtime.h>
#include <cmath>

#define NB 32
#define CH 384
#define IH 64
#define IW 64
#define OH 32
#define OW 32
#define PR 70   // padded rows: iy -3..66 -> pr 0..69
#define PW 36   // half-width entries (cols 0..34 used), padded for indexing

// ---------------------------------------------------------------------------
// Pass 1: 7x7 + 3x3 depthwise conv (stride 2). Writes y_lk into d_out,
// accumulates per-channel sum/sumsq for both branches.
// One block = one (n,c) plane. Thread = 4-output vertical strip.
// LDS is parity-split: sx2[0] = even padded cols, sx2[1] = odd padded cols,
// so lane ox reads stride-1 across the wave (conflict-free).
// ---------------------------------------------------------------------------
__global__ __launch_bounds__(256) void conv_stats_kernel(
    const float* __restrict__ x,
    const float* __restrict__ w_lk,
    const float* __restrict__ w_sk,
    float* __restrict__ ylk,     // = d_out, holds 7x7 branch pre-BN
    float* __restrict__ stats)   // [CH][4] = {sum_l, sumsq_l, sum_s, sumsq_s}
{
    __shared__ float sx2[2][PR][PW];
    __shared__ float sred[4 * 4];

    const int nc = blockIdx.x;
    const int c  = nc % CH;
    const float* xp = x + (size_t)nc * (IH * IW);
    const int tid = threadIdx.x;

    float* sflat = &sx2[0][0][0];
    for (int i = tid; i < 2 * PR * PW; i += 256) sflat[i] = 0.0f;
    __syncthreads();
    for (int i = tid; i < IH * IW; i += 256) {
        int r = i >> 6, col = i & 63;
        int cp = col + 3;                       // padded col
        sx2[cp & 1][r + 3][cp >> 1] = xp[i];
    }
    __syncthreads();

    // weights: uniform per block -> scalar loads, compile-time indexed
    float wl[49], ws9[9];
#pragma unroll
    for (int t = 0; t < 49; ++t) wl[t] = w_lk[c * 49 + t];
#pragma unroll
    for (int t = 0; t < 9; ++t)  ws9[t] = w_sk[c * 9 + t];

    const int ox  = tid & 31;
    const int oyq = tid >> 5;       // 0..7, strip of oy = 4*oyq..4*oyq+3
    const int pr0 = oyq * 8;        // first padded row needed

    float accl[4] = {0.f, 0.f, 0.f, 0.f};
    float accs[4] = {0.f, 0.f, 0.f, 0.f};

#pragma unroll
    for (int k = 0; k < 13; ++k) {
        const float e0 = sx2[0][pr0 + k][ox];
        const float o0 = sx2[1][pr0 + k][ox];
        const float e1 = sx2[0][pr0 + k][ox + 1];
        const float o1 = sx2[1][pr0 + k][ox + 1];
        const float e2 = sx2[0][pr0 + k][ox + 2];
        const float o2 = sx2[1][pr0 + k][ox + 2];
        const float e3 = sx2[0][pr0 + k][ox + 3];
#pragma unroll
        for (int j = 0; j < 4; ++j) {
            if (k >= 2 * j && k <= 2 * j + 6) {       // folds at compile time
                const int ky = k - 2 * j;
                accl[j] = fmaf(e0, wl[ky * 7 + 0], accl[j]);
                accl[j] = fmaf(o0, wl[ky * 7 + 1], accl[j]);
                accl[j] = fmaf(e1, wl[ky * 7 + 2], accl[j]);
                accl[j] = fmaf(o1, wl[ky * 7 + 3], accl[j]);
                accl[j] = fmaf(e2, wl[ky * 7 + 4], accl[j]);
                accl[j] = fmaf(o2, wl[ky * 7 + 5], accl[j]);
                accl[j] = fmaf(e3, wl[ky * 7 + 6], accl[j]);
            }
            if (k >= 2 * j + 2 && k <= 2 * j + 4) {
                const int ky = k - 2 * j - 2;
                accs[j] = fmaf(e1, ws9[ky * 3 + 0], accs[j]);
                accs[j] = fmaf(o1, ws9[ky * 3 + 1], accs[j]);
                accs[j] = fmaf(e2, ws9[ky * 3 + 2], accs[j]);
            }
        }
    }

    // store y_lk, accumulate stats
    float s0 = 0.f, s1 = 0.f, s2 = 0.f, s3 = 0.f;
    float* yp = ylk + (size_t)nc * (OH * OW);
#pragma unroll
    for (int j = 0; j < 4; ++j) {
        const int oy = oyq * 4 + j;
        yp[oy * OW + ox] = accl[j];
        s0 += accl[j]; s1 += accl[j] * accl[j];
        s2 += accs[j]; s3 += accs[j] * accs[j];
    }

#pragma unroll
    for (int off = 32; off >= 1; off >>= 1) {
        s0 += __shfl_down(s0, off);
        s1 += __shfl_down(s1, off);
        s2 += __shfl_down(s2, off);
        s3 += __shfl_down(s3, off);
    }
    const int wave = tid >> 6;
    if ((tid & 63) == 0) {
        sred[wave * 4 + 0] = s0; sred[wave * 4 + 1] = s1;
        sred[wave * 4 + 2] = s2; sred[wave * 4 + 3] = s3;
    }
    __syncthreads();
    if (tid == 0) {
        float t0 = 0.f, t1 = 0.f, t2 = 0.f, t3 = 0.f;
#pragma unroll
        for (int wv = 0; wv < 4; ++wv) {
            t0 += sred[wv * 4 + 0]; t1 += sred[wv * 4 + 1];
            t2 += sred[wv * 4 + 2]; t3 += sred[wv * 4 + 3];
        }
        atomicAdd(&stats[c * 4 + 0], t0);
        atomicAdd(&stats[c * 4 + 1], t1);
        atomicAdd(&stats[c * 4 + 2], t2);
        atomicAdd(&stats[c * 4 + 3], t3);
    }
}

// ---------------------------------------------------------------------------
// Pass 2: fold BN into per-channel scale/shift.
// ---------------------------------------------------------------------------
__global__ void finalize_kernel(
    const float* __restrict__ stats,
    const float* __restrict__ gamma_lk, const float* __restrict__ beta_lk,
    const float* __restrict__ gamma_sk, const float* __restrict__ beta_sk,
    float* __restrict__ params)  // [CH][4] = {sc_l, sh_l, sc_s, sh_s}
{
    const int c = blockIdx.x * blockDim.x + threadIdx.x;
    if (c >= CH) return;
    const float inv_cnt = 1.0f / (float)(NB * OH * OW);

    float mean_l = stats[c * 4 + 0] * inv_cnt;
    float var_l  = stats[c * 4 + 1] * inv_cnt - mean_l * mean_l;
    float sc_l   = gamma_lk[c] * rsqrtf(var_l + 1e-5f);
    float sh_l   = beta_lk[c] - mean_l * sc_l;

    float mean_s = stats[c * 4 + 2] * inv_cnt;
    float var_s  = stats[c * 4 + 3] * inv_cnt - mean_s * mean_s;
    float sc_s   = gamma_sk[c] * rsqrtf(var_s + 1e-5f);
    float sh_s   = beta_sk[c] - mean_s * sc_s;

    params[c * 4 + 0] = sc_l; params[c * 4 + 1] = sh_l;
    params[c * 4 + 2] = sc_s; params[c * 4 + 3] = sh_s;
}

// ---------------------------------------------------------------------------
// Pass 3: read y_lk from d_out, recompute cheap 3x3 from x (L3-resident),
// apply both BN affines, add, exact GELU, overwrite d_out in place.
// ---------------------------------------------------------------------------
__global__ __launch_bounds__(256) void apply_kernel(
    const float* __restrict__ x,
    const float* __restrict__ w_sk,
    const float* __restrict__ params,
    float* __restrict__ out)
{
    __shared__ float sx2[2][PR][PW];

    const int nc = blockIdx.x;
    const int c  = nc % CH;
    const float* xp = x + (size_t)nc * (IH * IW);
    const int tid = threadIdx.x;

    float* sflat = &sx2[0][0][0];
    for (int i = tid; i < 2 * PR * PW; i += 256) sflat[i] = 0.0f;
    __syncthreads();
    for (int i = tid; i < IH * IW; i += 256) {
        int r = i >> 6, col = i & 63;
        int cp = col + 3;
        sx2[cp & 1][r + 3][cp >> 1] = xp[i];
    }
    __syncthreads();

    float ws9[9];
#pragma unroll
    for (int t = 0; t < 9; ++t) ws9[t] = w_sk[c * 9 + t];

    const float sc_l = params[c * 4 + 0];
    const float sh_l = params[c * 4 + 1];
    const float sc_s = params[c * 4 + 2];
    const float sh_s = params[c * 4 + 3];

    const int ox  = tid & 31;
    const int oyq = tid >> 5;
    const int pr0 = oyq * 8;

    float accs[4] = {0.f, 0.f, 0.f, 0.f};
#pragma unroll
    for (int k = 2; k <= 10; ++k) {
        const float e1 = sx2[0][pr0 + k][ox + 1];
        const float o1 = sx2[1][pr0 + k][ox + 1];
        const float e2 = sx2[0][pr0 + k][ox + 2];
#pragma unroll
        for (int j = 0; j < 4; ++j) {
            if (k >= 2 * j + 2 && k <= 2 * j + 4) {
                const int ky = k - 2 * j - 2;
                accs[j] = fmaf(e1, ws9[ky * 3 + 0], accs[j]);
                accs[j] = fmaf(o1, ws9[ky * 3 + 1], accs[j]);
                accs[j] = fmaf(e2, ws9[ky * 3 + 2], accs[j]);
            }
        }
    }

    float* op = out + (size_t)nc * (OH * OW);
#pragma unroll
    for (int j = 0; j < 4; ++j) {
        const int oy = oyq * 4 + j;
        const int idx = oy * OW + ox;
        const float yl = op[idx];
        const float v  = fmaf(yl, sc_l, sh_l) + fmaf(accs[j], sc_s, sh_s);
        op[idx] = 0.5f * v * (1.0f + erff(v * 0.70710678118654752f));
    }
}

extern "C" void kernel_launch(void* const* d_in, const int* in_sizes, int n_in,
                              void* d_out, int out_size, void* d_ws, size_t ws_size,
                              hipStream_t stream) {
    const float* x        = (const float*)d_in[0];
    const float* w_lk     = (const float*)d_in[1];
    const float* gamma_lk = (const float*)d_in[2];
    const float* beta_lk  = (const float*)d_in[3];
    const float* w_sk     = (const float*)d_in[4];
    const float* gamma_sk = (const float*)d_in[5];
    const float* beta_sk  = (const float*)d_in[6];
    float* out = (float*)d_out;

    float* stats  = (float*)d_ws;        // CH*4 floats
    float* params = stats + CH * 4;      // CH*4 floats

    hipMemsetAsync(stats, 0, CH * 4 * sizeof(float), stream);

    conv_stats_kernel<<<NB * CH, 256, 0, stream>>>(x, w_lk, w_sk, out, stats);
    finalize_kernel<<<(CH + 255) / 256, 256, 0, stream>>>(
        stats, gamma_lk, beta_lk, gamma_sk, beta_sk, params);
    apply_kernel<<<NB * CH, 256, 0, stream>>>(x, w_sk, params, out);
}

// Round 3
// 87.777 us; speedup vs baseline: 1.9046x; 1.3828x over previous
//
#include <hip/hip_runtime.h>
#include <cmath>

#define NB 32
#define CH 384
#define IH 64
#define IW 64
#define OH 32
#define OW 32
#define PR 70   // padded rows: iy -3..66 -> pr 0..69
#define PW 36   // half-width entries (cols 0..34 used), padded for indexing

// ---------------------------------------------------------------------------
// Pass 1: 7x7 + 3x3 depthwise conv (stride 2). Writes y_lk -> d_out,
// y_sk -> workspace, accumulates per-channel sum/sumsq for both branches.
// One block = one (n,c) plane. Thread = 4-output vertical strip.
// LDS parity-split (even/odd padded cols) -> stride-1 lane access, no
// bank conflicts.
// ---------------------------------------------------------------------------
__global__ __launch_bounds__(256) void conv_stats_kernel(
    const float* __restrict__ x,
    const float* __restrict__ w_lk,
    const float* __restrict__ w_sk,
    float* __restrict__ ylk,     // = d_out, 7x7 branch pre-BN
    float* __restrict__ ysk,     // = ws,    3x3 branch pre-BN
    float* __restrict__ stats)   // [CH][4] = {sum_l, sumsq_l, sum_s, sumsq_s}
{
    __shared__ float sx2[2][PR][PW];
    __shared__ float sred[4 * 4];

    const int nc = blockIdx.x;
    const int c  = nc % CH;
    const float* xp = x + (size_t)nc * (IH * IW);
    const int tid = threadIdx.x;

    float* sflat = &sx2[0][0][0];
    for (int i = tid; i < 2 * PR * PW; i += 256) sflat[i] = 0.0f;
    __syncthreads();

    // float4 staging: 1024 float4 per plane, 4 per thread
    const float4* xp4 = (const float4*)xp;
#pragma unroll
    for (int it = 0; it < 4; ++it) {
        const int i = tid + it * 256;
        const float4 v = xp4[i];
        const int r = (i >> 4) + 3;      // 16 float4 per 64-wide row
        const int q = i & 15;            // cols 4q..4q+3, padded 4q+3..4q+6
        sx2[1][r][2 * q + 1] = v.x;      // cp = 4q+3 (odd)
        sx2[0][r][2 * q + 2] = v.y;      // cp = 4q+4 (even)
        sx2[1][r][2 * q + 2] = v.z;      // cp = 4q+5 (odd)
        sx2[0][r][2 * q + 3] = v.w;      // cp = 4q+6 (even)
    }
    __syncthreads();

    // weights: uniform per block -> scalar loads
    float wl[49], ws9[9];
#pragma unroll
    for (int t = 0; t < 49; ++t) wl[t] = w_lk[c * 49 + t];
#pragma unroll
    for (int t = 0; t < 9; ++t)  ws9[t] = w_sk[c * 9 + t];

    const int ox  = tid & 31;
    const int oyq = tid >> 5;       // 0..7, strip of oy = 4*oyq..4*oyq+3
    const int pr0 = oyq * 8;        // first padded row needed

    float accl[4] = {0.f, 0.f, 0.f, 0.f};
    float accs[4] = {0.f, 0.f, 0.f, 0.f};

#pragma unroll
    for (int k = 0; k < 13; ++k) {
        const float e0 = sx2[0][pr0 + k][ox];
        const float o0 = sx2[1][pr0 + k][ox];
        const float e1 = sx2[0][pr0 + k][ox + 1];
        const float o1 = sx2[1][pr0 + k][ox + 1];
        const float e2 = sx2[0][pr0 + k][ox + 2];
        const float o2 = sx2[1][pr0 + k][ox + 2];
        const float e3 = sx2[0][pr0 + k][ox + 3];
#pragma unroll
        for (int j = 0; j < 4; ++j) {
            if (k >= 2 * j && k <= 2 * j + 6) {       // folds at compile time
                const int ky = k - 2 * j;
                accl[j] = fmaf(e0, wl[ky * 7 + 0], accl[j]);
                accl[j] = fmaf(o0, wl[ky * 7 + 1], accl[j]);
                accl[j] = fmaf(e1, wl[ky * 7 + 2], accl[j]);
                accl[j] = fmaf(o1, wl[ky * 7 + 3], accl[j]);
                accl[j] = fmaf(e2, wl[ky * 7 + 4], accl[j]);
                accl[j] = fmaf(o2, wl[ky * 7 + 5], accl[j]);
                accl[j] = fmaf(e3, wl[ky * 7 + 6], accl[j]);
            }
            if (k >= 2 * j + 2 && k <= 2 * j + 4) {
                const int ky = k - 2 * j - 2;
                accs[j] = fmaf(e1, ws9[ky * 3 + 0], accs[j]);
                accs[j] = fmaf(o1, ws9[ky * 3 + 1], accs[j]);
                accs[j] = fmaf(e2, ws9[ky * 3 + 2], accs[j]);
            }
        }
    }

    // store both branches, accumulate stats
    float s0 = 0.f, s1 = 0.f, s2 = 0.f, s3 = 0.f;
    float* ylp = ylk + (size_t)nc * (OH * OW);
    float* ysp = ysk + (size_t)nc * (OH * OW);
#pragma unroll
    for (int j = 0; j < 4; ++j) {
        const int oy = oyq * 4 + j;
        ylp[oy * OW + ox] = accl[j];
        ysp[oy * OW + ox] = accs[j];
        s0 += accl[j]; s1 += accl[j] * accl[j];
        s2 += accs[j]; s3 += accs[j] * accs[j];
    }

#pragma unroll
    for (int off = 32; off >= 1; off >>= 1) {
        s0 += __shfl_down(s0, off);
        s1 += __shfl_down(s1, off);
        s2 += __shfl_down(s2, off);
        s3 += __shfl_down(s3, off);
    }
    const int wave = tid >> 6;
    if ((tid & 63) == 0) {
        sred[wave * 4 + 0] = s0; sred[wave * 4 + 1] = s1;
        sred[wave * 4 + 2] = s2; sred[wave * 4 + 3] = s3;
    }
    __syncthreads();
    if (tid == 0) {
        float t0 = 0.f, t1 = 0.f, t2 = 0.f, t3 = 0.f;
#pragma unroll
        for (int wv = 0; wv < 4; ++wv) {
            t0 += sred[wv * 4 + 0]; t1 += sred[wv * 4 + 1];
            t2 += sred[wv * 4 + 2]; t3 += sred[wv * 4 + 3];
        }
        atomicAdd(&stats[c * 4 + 0], t0);
        atomicAdd(&stats[c * 4 + 1], t1);
        atomicAdd(&stats[c * 4 + 2], t2);
        atomicAdd(&stats[c * 4 + 3], t3);
    }
}

// ---------------------------------------------------------------------------
// Pass 2: fold BN into per-channel scale/shift.
// ---------------------------------------------------------------------------
__global__ void finalize_kernel(
    const float* __restrict__ stats,
    const float* __restrict__ gamma_lk, const float* __restrict__ beta_lk,
    const float* __restrict__ gamma_sk, const float* __restrict__ beta_sk,
    float* __restrict__ params)  // [CH][4] = {sc_l, sh_l, sc_s, sh_s}
{
    const int c = blockIdx.x * blockDim.x + threadIdx.x;
    if (c >= CH) return;
    const float inv_cnt = 1.0f / (float)(NB * OH * OW);

    float mean_l = stats[c * 4 + 0] * inv_cnt;
    float var_l  = stats[c * 4 + 1] * inv_cnt - mean_l * mean_l;
    float sc_l   = gamma_lk[c] * rsqrtf(var_l + 1e-5f);
    float sh_l   = beta_lk[c] - mean_l * sc_l;

    float mean_s = stats[c * 4 + 2] * inv_cnt;
    float var_s  = stats[c * 4 + 3] * inv_cnt - mean_s * mean_s;
    float sc_s   = gamma_sk[c] * rsqrtf(var_s + 1e-5f);
    float sh_s   = beta_sk[c] - mean_s * sc_s;

    params[c * 4 + 0] = sc_l; params[c * 4 + 1] = sh_l;
    params[c * 4 + 2] = sc_s; params[c * 4 + 3] = sh_s;
}

// ---------------------------------------------------------------------------
// Pass 3: pure elementwise — affine both branches, add, exact GELU.
// float4 vectorized; each float4 lies within one channel plane (1024 | 4).
// ---------------------------------------------------------------------------
#define N4 (NB * CH * OH * OW / 4)   // 3,145,728 float4

__global__ __launch_bounds__(256) void apply_kernel(
    const float4* __restrict__ ysk,
    const float* __restrict__ params,
    float4* __restrict__ out)        // in-place: reads y_lk, writes result
{
    int i = blockIdx.x * 256 + threadIdx.x;
    const int stride = gridDim.x * 256;
    for (; i < N4; i += stride) {
        const int c = (i >> 8) % CH;            // (elem>>10)%CH, elem = 4*i
        const float sc_l = params[c * 4 + 0];
        const float sh_l = params[c * 4 + 1];
        const float sc_s = params[c * 4 + 2];
        const float sh_s = params[c * 4 + 3];
        const float4 a = out[i];
        const float4 b = ysk[i];
        float v0 = fmaf(a.x, sc_l, sh_l) + fmaf(b.x, sc_s, sh_s);
        float v1 = fmaf(a.y, sc_l, sh_l) + fmaf(b.y, sc_s, sh_s);
        float v2 = fmaf(a.z, sc_l, sh_l) + fmaf(b.z, sc_s, sh_s);
        float v3 = fmaf(a.w, sc_l, sh_l) + fmaf(b.w, sc_s, sh_s);
        float4 r;
        r.x = 0.5f * v0 * (1.0f + erff(v0 * 0.70710678118654752f));
        r.y = 0.5f * v1 * (1.0f + erff(v1 * 0.70710678118654752f));
        r.z = 0.5f * v2 * (1.0f + erff(v2 * 0.70710678118654752f));
        r.w = 0.5f * v3 * (1.0f + erff(v3 * 0.70710678118654752f));
        out[i] = r;
    }
}

extern "C" void kernel_launch(void* const* d_in, const int* in_sizes, int n_in,
                              void* d_out, int out_size, void* d_ws, size_t ws_size,
                              hipStream_t stream) {
    const float* x        = (const float*)d_in[0];
    const float* w_lk     = (const float*)d_in[1];
    const float* gamma_lk = (const float*)d_in[2];
    const float* beta_lk  = (const float*)d_in[3];
    const float* w_sk     = (const float*)d_in[4];
    const float* gamma_sk = (const float*)d_in[5];
    const float* beta_sk  = (const float*)d_in[6];
    float* out = (float*)d_out;

    float* stats  = (float*)d_ws;            // CH*4 floats
    float* params = stats + CH * 4;          // CH*4 floats
    float* ysk    = params + CH * 4;         // NB*CH*OH*OW floats (50 MB), 16B-aligned

    hipMemsetAsync(stats, 0, CH * 4 * sizeof(float), stream);

    conv_stats_kernel<<<NB * CH, 256, 0, stream>>>(x, w_lk, w_sk, out, ysk, stats);
    finalize_kernel<<<(CH + 255) / 256, 256, 0, stream>>>(
        stats, gamma_lk, beta_lk, gamma_sk, beta_sk, params);
    apply_kernel<<<4096, 256, 0, stream>>>((const float4*)ysk, params, (float4*)out);
}

// Round 4
// 80.204 us; speedup vs baseline: 2.0844x; 1.0944x over previous
//
#include <hip/hip_runtime.h>
#include <hip/hip_fp16.h>
#include <cmath>

#define NB 32
#define CH 384
#define IH 64
#define IW 64
#define OH 32
#define OW 32
#define PR 70   // padded rows: iy -3..66 -> pr 0..69
#define PW 36   // half-width entries (cols 0..34 used), padded for indexing

// ---------------------------------------------------------------------------
// Pass 1: 7x7 + 3x3 depthwise conv (stride 2). Writes packed half2{y_lk,y_sk}
// to workspace, accumulates per-channel fp32 sum/sumsq for both branches.
// One block = one (n,c) plane. Thread = 4-output vertical strip.
// LDS parity-split (even/odd padded cols) -> stride-1 lane access (2-way = free).
// ---------------------------------------------------------------------------
__global__ __launch_bounds__(256) void conv_stats_kernel(
    const float* __restrict__ x,
    const float* __restrict__ w_lk,
    const float* __restrict__ w_sk,
    __half2* __restrict__ yls,   // ws: per-pixel {y_lk, y_sk} fp16
    float* __restrict__ stats)   // [CH][4] = {sum_l, sumsq_l, sum_s, sumsq_s}
{
    __shared__ float sx2[2][PR][PW];
    __shared__ float sred[4 * 4];

    const int nc = blockIdx.x;
    const int c  = nc % CH;
    const float* xp = x + (size_t)nc * (IH * IW);
    const int tid = threadIdx.x;

    float* sflat = &sx2[0][0][0];
    for (int i = tid; i < 2 * PR * PW; i += 256) sflat[i] = 0.0f;
    __syncthreads();

    // float4 staging: 1024 float4 per plane, 4 per thread
    const float4* xp4 = (const float4*)xp;
#pragma unroll
    for (int it = 0; it < 4; ++it) {
        const int i = tid + it * 256;
        const float4 v = xp4[i];
        const int r = (i >> 4) + 3;      // 16 float4 per 64-wide row
        const int q = i & 15;            // cols 4q..4q+3, padded 4q+3..4q+6
        sx2[1][r][2 * q + 1] = v.x;      // cp = 4q+3 (odd)
        sx2[0][r][2 * q + 2] = v.y;      // cp = 4q+4 (even)
        sx2[1][r][2 * q + 2] = v.z;      // cp = 4q+5 (odd)
        sx2[0][r][2 * q + 3] = v.w;      // cp = 4q+6 (even)
    }
    __syncthreads();

    // weights: uniform per block -> scalar loads
    float wl[49], ws9[9];
#pragma unroll
    for (int t = 0; t < 49; ++t) wl[t] = w_lk[c * 49 + t];
#pragma unroll
    for (int t = 0; t < 9; ++t)  ws9[t] = w_sk[c * 9 + t];

    const int ox  = tid & 31;
    const int oyq = tid >> 5;       // 0..7, strip of oy = 4*oyq..4*oyq+3
    const int pr0 = oyq * 8;        // first padded row needed

    float accl[4] = {0.f, 0.f, 0.f, 0.f};
    float accs[4] = {0.f, 0.f, 0.f, 0.f};

#pragma unroll
    for (int k = 0; k < 13; ++k) {
        const float e0 = sx2[0][pr0 + k][ox];
        const float o0 = sx2[1][pr0 + k][ox];
        const float e1 = sx2[0][pr0 + k][ox + 1];
        const float o1 = sx2[1][pr0 + k][ox + 1];
        const float e2 = sx2[0][pr0 + k][ox + 2];
        const float o2 = sx2[1][pr0 + k][ox + 2];
        const float e3 = sx2[0][pr0 + k][ox + 3];
#pragma unroll
        for (int j = 0; j < 4; ++j) {
            if (k >= 2 * j && k <= 2 * j + 6) {       // folds at compile time
                const int ky = k - 2 * j;
                accl[j] = fmaf(e0, wl[ky * 7 + 0], accl[j]);
                accl[j] = fmaf(o0, wl[ky * 7 + 1], accl[j]);
                accl[j] = fmaf(e1, wl[ky * 7 + 2], accl[j]);
                accl[j] = fmaf(o1, wl[ky * 7 + 3], accl[j]);
                accl[j] = fmaf(e2, wl[ky * 7 + 4], accl[j]);
                accl[j] = fmaf(o2, wl[ky * 7 + 5], accl[j]);
                accl[j] = fmaf(e3, wl[ky * 7 + 6], accl[j]);
            }
            if (k >= 2 * j + 2 && k <= 2 * j + 4) {
                const int ky = k - 2 * j - 2;
                accs[j] = fmaf(e1, ws9[ky * 3 + 0], accs[j]);
                accs[j] = fmaf(o1, ws9[ky * 3 + 1], accs[j]);
                accs[j] = fmaf(e2, ws9[ky * 3 + 2], accs[j]);
            }
        }
    }

    // store packed branches (fp16), accumulate fp32 stats
    float s0 = 0.f, s1 = 0.f, s2 = 0.f, s3 = 0.f;
    __half2* yp = yls + (size_t)nc * (OH * OW);
#pragma unroll
    for (int j = 0; j < 4; ++j) {
        const int oy = oyq * 4 + j;
        yp[oy * OW + ox] = __floats2half2_rn(accl[j], accs[j]);
        s0 += accl[j]; s1 += accl[j] * accl[j];
        s2 += accs[j]; s3 += accs[j] * accs[j];
    }

#pragma unroll
    for (int off = 32; off >= 1; off >>= 1) {
        s0 += __shfl_down(s0, off);
        s1 += __shfl_down(s1, off);
        s2 += __shfl_down(s2, off);
        s3 += __shfl_down(s3, off);
    }
    const int wave = tid >> 6;
    if ((tid & 63) == 0) {
        sred[wave * 4 + 0] = s0; sred[wave * 4 + 1] = s1;
        sred[wave * 4 + 2] = s2; sred[wave * 4 + 3] = s3;
    }
    __syncthreads();
    if (tid == 0) {
        float t0 = 0.f, t1 = 0.f, t2 = 0.f, t3 = 0.f;
#pragma unroll
        for (int wv = 0; wv < 4; ++wv) {
            t0 += sred[wv * 4 + 0]; t1 += sred[wv * 4 + 1];
            t2 += sred[wv * 4 + 2]; t3 += sred[wv * 4 + 3];
        }
        atomicAdd(&stats[c * 4 + 0], t0);
        atomicAdd(&stats[c * 4 + 1], t1);
        atomicAdd(&stats[c * 4 + 2], t2);
        atomicAdd(&stats[c * 4 + 3], t3);
    }
}

// ---------------------------------------------------------------------------
// Pass 2: fold BN into per-channel scale/shift.
// ---------------------------------------------------------------------------
__global__ void finalize_kernel(
    const float* __restrict__ stats,
    const float* __restrict__ gamma_lk, const float* __restrict__ beta_lk,
    const float* __restrict__ gamma_sk, const float* __restrict__ beta_sk,
    float* __restrict__ params)  // [CH][4] = {sc_l, sh_l, sc_s, sh_s}
{
    const int c = blockIdx.x * blockDim.x + threadIdx.x;
    if (c >= CH) return;
    const float inv_cnt = 1.0f / (float)(NB * OH * OW);

    float mean_l = stats[c * 4 + 0] * inv_cnt;
    float var_l  = stats[c * 4 + 1] * inv_cnt - mean_l * mean_l;
    float sc_l   = gamma_lk[c] * rsqrtf(var_l + 1e-5f);
    float sh_l   = beta_lk[c] - mean_l * sc_l;

    float mean_s = stats[c * 4 + 2] * inv_cnt;
    float var_s  = stats[c * 4 + 3] * inv_cnt - mean_s * mean_s;
    float sc_s   = gamma_sk[c] * rsqrtf(var_s + 1e-5f);
    float sh_s   = beta_sk[c] - mean_s * sc_s;

    params[c * 4 + 0] = sc_l; params[c * 4 + 1] = sh_l;
    params[c * 4 + 2] = sc_s; params[c * 4 + 3] = sh_s;
}

// ---------------------------------------------------------------------------
// Pass 3: pure elementwise — unpack 4 half2 pixels per uint4 (16 B/lane),
// affine both branches, add, exact GELU, write float4.
// Each 4-pixel group lies within one channel plane (1024 | 4).
// ---------------------------------------------------------------------------
#define N4 (NB * CH * OH * OW / 4)   // 3,145,728 groups of 4 pixels

__global__ __launch_bounds__(256) void apply_kernel(
    const uint4* __restrict__ yls4,
    const float* __restrict__ params,
    float4* __restrict__ out)
{
    int i = blockIdx.x * 256 + threadIdx.x;
    const int stride = gridDim.x * 256;
    for (; i < N4; i += stride) {
        const int c = (i >> 8) % CH;            // pixel = 4*i, c = (pixel>>10)%CH
        const float sc_l = params[c * 4 + 0];
        const float sh_l = params[c * 4 + 1];
        const float sc_s = params[c * 4 + 2];
        const float sh_s = params[c * 4 + 3];

        const uint4 v = yls4[i];
        const __half2 h0 = *reinterpret_cast<const __half2*>(&v.x);
        const __half2 h1 = *reinterpret_cast<const __half2*>(&v.y);
        const __half2 h2 = *reinterpret_cast<const __half2*>(&v.z);
        const __half2 h3 = *reinterpret_cast<const __half2*>(&v.w);

        float v0 = fmaf(__low2float(h0), sc_l, sh_l) + fmaf(__high2float(h0), sc_s, sh_s);
        float v1 = fmaf(__low2float(h1), sc_l, sh_l) + fmaf(__high2float(h1), sc_s, sh_s);
        float v2 = fmaf(__low2float(h2), sc_l, sh_l) + fmaf(__high2float(h2), sc_s, sh_s);
        float v3 = fmaf(__low2float(h3), sc_l, sh_l) + fmaf(__high2float(h3), sc_s, sh_s);

        float4 r;
        r.x = 0.5f * v0 * (1.0f + erff(v0 * 0.70710678118654752f));
        r.y = 0.5f * v1 * (1.0f + erff(v1 * 0.70710678118654752f));
        r.z = 0.5f * v2 * (1.0f + erff(v2 * 0.70710678118654752f));
        r.w = 0.5f * v3 * (1.0f + erff(v3 * 0.70710678118654752f));
        out[i] = r;
    }
}

extern "C" void kernel_launch(void* const* d_in, const int* in_sizes, int n_in,
                              void* d_out, int out_size, void* d_ws, size_t ws_size,
                              hipStream_t stream) {
    const float* x        = (const float*)d_in[0];
    const float* w_lk     = (const float*)d_in[1];
    const float* gamma_lk = (const float*)d_in[2];
    const float* beta_lk  = (const float*)d_in[3];
    const float* w_sk     = (const float*)d_in[4];
    const float* gamma_sk = (const float*)d_in[5];
    const float* beta_sk  = (const float*)d_in[6];
    float* out = (float*)d_out;

    float* stats  = (float*)d_ws;            // CH*4 floats
    float* params = stats + CH * 4;          // CH*4 floats
    __half2* yls  = (__half2*)(params + CH * 4);  // NB*CH*OH*OW half2 (50 MB), 16B-aligned

    hipMemsetAsync(stats, 0, CH * 4 * sizeof(float), stream);

    conv_stats_kernel<<<NB * CH, 256, 0, stream>>>(x, w_lk, w_sk, yls, stats);
    finalize_kernel<<<(CH + 255) / 256, 256, 0, stream>>>(
        stats, gamma_lk, beta_lk, gamma_sk, beta_sk, params);
    apply_kernel<<<4096, 256, 0, stream>>>((const uint4*)yls, params, (float4*)out);
}